// Round 19
// baseline (125.401 us; speedup 1.0000x reference)
//
#include <hip/hip_runtime.h>
#include <hip/hip_fp16.h>
#include <cstddef>

#define NN 256
#define DD 1024
#define CC 4
#define NP 46
#define NT 512
#define ROOT (NN - 1)

typedef unsigned int uint4v __attribute__((ext_vector_type(4)));

// Blocked transposed fp16 params, rebuilt every launch:
//   g_Pth[((dep*16 + jt)*16 + rt)*4096 + jq*64 + rq] = (half)P[dep][rt*64+rq][jt*64+jq]
// Pure function of d_in -> identical across graph replays. Walk math stays fp32.
__device__ __half g_Pth[NP * DD * DD];

// ---- Kernel A: 64x64 tile transpose fp32 -> fp16, blocked destination ----
// Reads: 64 x 256B contiguous row spans (coalesced). Writes: ONE contiguous
// 8KB tile per block (2KB contiguous per wave-store), nontemporal.
__global__ __launch_bounds__(256) void transpose_kernel(
    const float* __restrict__ par) {
  __shared__ float tile[64][65];
  const int b = blockIdx.x;        // p*256 + t
  const int p = b >> 8;
  const int t = b & 255;
  const int jt = t >> 4;           // dest j-tile (source col-tile)
  const int rt = t & 15;           // source row-tile
  const int tid = threadIdx.x;
  const float* src = par + ((size_t)p << 20) + ((size_t)(rt << 6) << 10) + (jt << 6);
  __half* dst = g_Pth + (((size_t)(p << 4) + jt) * 16 + rt) * 4096;

#pragma unroll
  for (int k = 0; k < 4; ++k) {
    const int idx = tid + (k << 8);      // float4 id 0..1023
    const int row = idx >> 4;            // 0..63 (source row within tile)
    const int c4 = (idx & 15) << 2;      // 0..60 (source col within tile)
    const float4 v = *(const float4*)(src + (size_t)row * DD + c4);
    tile[row][c4 + 0] = v.x;
    tile[row][c4 + 1] = v.y;
    tile[row][c4 + 2] = v.z;
    tile[row][c4 + 3] = v.w;
  }
  __syncthreads();

  // Thread tid writes dest elements [jq][rq0..rq0+15]: 32B contiguous.
  const int jq = tid >> 2;
  const int rq0 = (tid & 3) << 4;
  unsigned int h[8];
#pragma unroll
  for (int i = 0; i < 8; ++i) {
    const __half2 hh =
        __floats2half2_rn(tile[rq0 + 2 * i][jq], tile[rq0 + 2 * i + 1][jq]);
    h[i] = *(const unsigned int*)&hh;
  }
  uint4v a = {h[0], h[1], h[2], h[3]};
  uint4v bq = {h[4], h[5], h[6], h[7]};
  __half* op = dst + (jq << 6) + rq0;
  __builtin_nontemporal_store(a, (uint4v*)op);
  __builtin_nontemporal_store(bq, (uint4v*)(op + 8));
}

// ---- Kernel B: column-split serial walk over blocked fp16 Pt ----
struct St {
  float2 p0, p1, p2, p3;  // P[dep][r2, r2+1][j0+c] for c = 0..3
  float x0, x1;           // emb[node][r2], emb[node][r2+1] (last-child only)
};

__device__ __forceinline__ float4 relu4(float4 v) {
  float4 r;
  r.x = fmaxf(v.x, 0.f); r.y = fmaxf(v.y, 0.f);
  r.z = fmaxf(v.z, 0.f); r.w = fmaxf(v.w, 0.f);
  return r;
}

// thr_off = rt*4096 + jq*64 + rq (thread-constant); jt16 = (j0>>6)<<4.
__device__ __forceinline__ void ld_stage(St& S, int e,
                                         const __half* __restrict__ pt,
                                         const float* __restrict__ emb,
                                         const short* e_meta, const short* e_node,
                                         int jt16, int thr_off, int r2) {
  const int meta = e_meta[e];
  const int dep = meta & 0x1FFF;
  const __half* hb = pt + (((size_t)(dep << 8) + jt16) << 12) + thr_off;
  S.p0 = __half22float2(*(const __half2*)(hb));
  S.p1 = __half22float2(*(const __half2*)(hb + 64));
  S.p2 = __half22float2(*(const __half2*)(hb + 128));
  S.p3 = __half22float2(*(const __half2*)(hb + 192));
  if (meta & 0x8000) {
    const float2 xx = *(const float2*)(emb + (((size_t)e_node[e]) << 10) + r2);
    S.x0 = xx.x; S.x1 = xx.y;
  }
}

__device__ __forceinline__ float2 mul2s(float2 a, float s) {
  float2 r; r.x = a.x * s; r.y = a.y * s; return r;
}
__device__ __forceinline__ float2 max2(float2 a, float2 b) {
  float2 r; r.x = fmaxf(a.x, b.x); r.y = fmaxf(a.y, b.y); return r;
}

__device__ __forceinline__ void cmp_stage(const St& S, int e, float2& m0, float2& m1,
                                          float2& m2, float2& m3,
                                          float (*z_loc)[4], float (*s_part)[4],
                                          const short* e_child, const short* e_meta,
                                          const short* e_node, int tid) {
  const int meta = e_meta[e];
  const float4 u = relu4(*(const float4*)z_loc[e_child[e]]);  // 4 cols
  if (meta & (1 << 14)) {  // first child of node
    m0 = mul2s(S.p0, u.x); m1 = mul2s(S.p1, u.y);
    m2 = mul2s(S.p2, u.z); m3 = mul2s(S.p3, u.w);
  } else {
    m0 = max2(m0, mul2s(S.p0, u.x)); m1 = max2(m1, mul2s(S.p1, u.y));
    m2 = max2(m2, mul2s(S.p2, u.z)); m3 = max2(m3, mul2s(S.p3, u.w));
  }
  if (meta & 0x8000) {  // last child: finish node
    float4 acc;
    acc.x = fmaf(S.x1, m0.y, S.x0 * m0.x);
    acc.y = fmaf(S.x1, m1.y, S.x0 * m1.x);
    acc.z = fmaf(S.x1, m2.y, S.x0 * m2.x);
    acc.w = fmaf(S.x1, m3.y, S.x0 * m3.x);
    // 64-lane butterfly (fixed order -> deterministic)
#pragma unroll
    for (int off = 1; off < 64; off <<= 1) {
      acc.x += __shfl_xor(acc.x, off, 64);
      acc.y += __shfl_xor(acc.y, off, 64);
      acc.z += __shfl_xor(acc.z, off, 64);
      acc.w += __shfl_xor(acc.w, off, 64);
    }
    if ((tid & 63) == 0) *(float4*)s_part[tid >> 6] = acc;
    __syncthreads();
    if (tid < 4) {
      float s = 0.f;
#pragma unroll
      for (int k = 0; k < 8; ++k) s += s_part[k][tid];
      z_loc[e_node[e]][tid] = s;
    }
    __syncthreads();
  }
}

__global__ __launch_bounds__(NT, 1) void walk_kernel(
    const float* __restrict__ emb, const int* __restrict__ cidx,
    const int* __restrict__ cdep, const unsigned char* __restrict__ cmask,
    float* __restrict__ out) {
  __shared__ float z_loc[NN][4];
  __shared__ short s_ci[NN][CC];
  __shared__ short s_cd[NN][CC];
  __shared__ short s_nc[NN];
  __shared__ int s_pfx[NN];
  __shared__ unsigned char s_reach[NN];
  __shared__ short s_e_child[NN * CC];  // child-stream (topo order)
  __shared__ short s_e_meta[NN * CC];   // dep | first<<14 | last<<15
  __shared__ short s_e_node[NN * CC];
  __shared__ int s_NE;
  __shared__ int s_flag;
  __shared__ float s_part[8][4];

  const int tid = threadIdx.x;
  const int j0 = blockIdx.x << 2;  // 4 exclusive columns per block
  const int r2 = tid << 1;         // 2 rows per thread
  const __half* pt = g_Pth;
  // Blocked-layout coordinates (thread constants)
  const int jt16 = (j0 >> 6) << 4;
  const int thr_off = ((r2 >> 6) << 12) + ((j0 & 63) << 6) + (r2 & 63);

  // ---- Phase 1: schedule build (LDS only, identical in every block) ----
  if (tid == 0)
    s_flag = (cmask[1021] == 1 && cmask[1022] == 1 && cmask[1023] == 1);
  __syncthreads();
  const bool m_u8 = (s_flag != 0);
  const int* m32 = (const int*)cmask;
  if (tid < NN) {
    int nc = 0;
#pragma unroll
    for (int c = 0; c < CC; ++c) {
      bool mk = m_u8 ? (cmask[tid * CC + c] != 0) : (m32[tid * CC + c] != 0);
      if (mk) {
        s_ci[tid][nc] = (short)cidx[tid * CC + c];
        s_cd[tid][nc] = (short)cdep[tid * CC + c];
        ++nc;
      }
    }
    s_nc[tid] = (short)nc;
    s_reach[tid] = (tid == ROOT) ? 1 : 0;
  }
  __syncthreads();

  // Reachability fixpoint (root downward; <= depth passes)
  for (int it = 0; it < NN + 2; ++it) {
    if (tid == 0) s_flag = 0;
    __syncthreads();
    if (tid < NN && s_reach[tid] && s_nc[tid] > 0) {
      for (int c = 0; c < s_nc[tid]; ++c) {
        const int ch = s_ci[tid][c];
        if (!s_reach[ch]) { s_reach[ch] = 1; s_flag = 1; }
      }
    }
    __syncthreads();
    const int chg = s_flag;
    __syncthreads();
    if (!chg) break;
  }

  // Prefix-sum of per-node child counts (reachable internal only)
  const int wgt = (tid < NN && s_reach[tid] && s_nc[tid] > 0) ? (int)s_nc[tid] : 0;
  if (tid < NN) s_pfx[tid] = wgt;
  __syncthreads();
  for (int off = 1; off < NN; off <<= 1) {
    int v = 0;
    if (tid < NN && tid >= off) v = s_pfx[tid - off];
    __syncthreads();
    if (tid < NN) s_pfx[tid] += v;
    __syncthreads();
  }
  // Emit child-stream entries (ascending node index = topological order)
  if (tid < NN && wgt > 0) {
    const int st = s_pfx[tid] - wgt;
    for (int c = 0; c < wgt; ++c) {
      s_e_child[st + c] = s_ci[tid][c];
      int meta = (int)s_cd[tid][c];
      if (c == 0) meta |= 1 << 14;
      if (c == wgt - 1) meta |= 1 << 15;
      s_e_meta[st + c] = (short)meta;
      s_e_node[st + c] = (short)tid;
    }
  }
  if (tid == NN - 1) s_NE = s_pfx[NN - 1];

  // Init z_loc from embeddings (leaf z = x; internal overwritten in topo order)
  if (tid < NN) {
    const float4 e = *(const float4*)(emb + (((size_t)tid) << 10) + j0);
    *(float4*)z_loc[tid] = e;
  }
  __syncthreads();
  const int NE = s_NE;

  // ---- Phase 2: 4-deep pipelined serial walk (static stage names) ----
  St A, B, C, D;
  float2 m0, m1, m2, m3;
  if (NE > 0) ld_stage(A, 0, pt, emb, s_e_meta, s_e_node, jt16, thr_off, r2);
  if (NE > 1) ld_stage(B, 1, pt, emb, s_e_meta, s_e_node, jt16, thr_off, r2);
  if (NE > 2) ld_stage(C, 2, pt, emb, s_e_meta, s_e_node, jt16, thr_off, r2);
  int e = 0;
  while (e < NE) {
    if (e + 3 < NE) ld_stage(D, e + 3, pt, emb, s_e_meta, s_e_node, jt16, thr_off, r2);
    cmp_stage(A, e, m0, m1, m2, m3, z_loc, s_part, s_e_child, s_e_meta, s_e_node, tid);
    if (++e >= NE) break;
    if (e + 3 < NE) ld_stage(A, e + 3, pt, emb, s_e_meta, s_e_node, jt16, thr_off, r2);
    cmp_stage(B, e, m0, m1, m2, m3, z_loc, s_part, s_e_child, s_e_meta, s_e_node, tid);
    if (++e >= NE) break;
    if (e + 3 < NE) ld_stage(B, e + 3, pt, emb, s_e_meta, s_e_node, jt16, thr_off, r2);
    cmp_stage(C, e, m0, m1, m2, m3, z_loc, s_part, s_e_child, s_e_meta, s_e_node, tid);
    if (++e >= NE) break;
    if (e + 3 < NE) ld_stage(C, e + 3, pt, emb, s_e_meta, s_e_node, jt16, thr_off, r2);
    cmp_stage(D, e, m0, m1, m2, m3, z_loc, s_part, s_e_child, s_e_meta, s_e_node, tid);
    ++e;
  }

  // ---- Output: root z for this block's 4 columns ----
  if (tid < 4) out[j0 + tid] = z_loc[ROOT][tid];
}

extern "C" void kernel_launch(void* const* d_in, const int* in_sizes, int n_in,
                              void* d_out, int out_size, void* d_ws, size_t ws_size,
                              hipStream_t stream) {
  const float* emb = (const float*)d_in[0];
  const float* par = (const float*)d_in[1];
  const int* cidx = (const int*)d_in[2];
  const int* cdep = (const int*)d_in[3];
  const unsigned char* cmask = (const unsigned char*)d_in[4];
  float* out = (float*)d_out;

  hipLaunchKernelGGL(transpose_kernel, dim3(NP * 256), dim3(256), 0, stream, par);
  hipLaunchKernelGGL(walk_kernel, dim3(256), dim3(NT), 0, stream, emb, cidx,
                     cdep, cmask, out);
}

// Round 20
// 112.367 us; speedup vs baseline: 1.1160x; 1.1160x over previous
//
#include <hip/hip_runtime.h>
#include <hip/hip_fp16.h>
#include <cstddef>

#define NN 256
#define DD 1024
#define CC 4
#define NP 46
#define NT 512
#define ROOT (NN - 1)
#define PT_BYTES ((size_t)NP * DD * DD * sizeof(__half))

// Fallback destination if ws_size < PT_BYTES (never expected). Pt is rebuilt
// from d_in every launch -> pure function of inputs, replay-safe either way.
__device__ __half g_Pth_fallback[NP * DD * DD];

// ---- Kernel A: LDS-tiled transpose fp32 -> fp16 (R18 structure) ----
// Pt[p][j][r] = (half)P[p][r][j]. Both global sides coalesced; NT stores.
__global__ __launch_bounds__(256) void transpose_kernel(
    const float* __restrict__ par, __half* __restrict__ ptile) {
  __shared__ float tile[128][65];
  const int b = blockIdx.x;        // p*128 + t
  const int p = b >> 7;
  const int t = b & 127;
  const int tr = (t >> 4) << 7;    // tile row origin in P (8 x 128)
  const int tc = (t & 15) << 6;    // tile col origin in P (16 x 64)
  const int tid = threadIdx.x;
  const float* src = par + ((size_t)p << 20);
  __half* dst = ptile + ((size_t)p << 20);

#pragma unroll
  for (int k = 0; k < 8; ++k) {
    const int idx = tid + (k << 8);      // float4 id 0..2047
    const int row = idx >> 4;            // 0..127
    const int c4 = (idx & 15) << 2;      // 0..60
    const float4 v = *(const float4*)(src + (size_t)(tr + row) * DD + tc + c4);
    tile[row][c4 + 0] = v.x;
    tile[row][c4 + 1] = v.y;
    tile[row][c4 + 2] = v.z;
    tile[row][c4 + 3] = v.w;
  }
  __syncthreads();

  const int l = tid & 63;
  const int cb = (tid >> 6) << 4;        // wave's out-row base (16 rows/wave)
  const int r4 = (l & 31) << 2;          // 4-row chunk within out-row
#pragma unroll
  for (int m = 0; m < 8; ++m) {
    const int c = cb + (m << 1) + (l >> 5);   // out-row (= P column) in tile
    const __half2 h01 = __floats2half2_rn(tile[r4 + 0][c], tile[r4 + 1][c]);
    const __half2 h23 = __floats2half2_rn(tile[r4 + 2][c], tile[r4 + 3][c]);
    const unsigned int u0 = *(const unsigned int*)&h01;
    const unsigned int u1 = *(const unsigned int*)&h23;
    const unsigned long long u =
        (unsigned long long)u0 | ((unsigned long long)u1 << 32);
    __builtin_nontemporal_store(
        u, (unsigned long long*)(dst + (size_t)(tc + c) * DD + tr + r4));
  }
}

// ---- Kernel B: column-split serial walk over fp16 Pt (fp32 arithmetic) ----
struct St {
  float2 p0, p1, p2, p3;  // Pt[dep][j0+c][r2, r2+1] for c = 0..3
  float x0, x1;           // emb[node][r2], emb[node][r2+1] (last-child only)
};

__device__ __forceinline__ float4 relu4(float4 v) {
  float4 r;
  r.x = fmaxf(v.x, 0.f); r.y = fmaxf(v.y, 0.f);
  r.z = fmaxf(v.z, 0.f); r.w = fmaxf(v.w, 0.f);
  return r;
}

__device__ __forceinline__ void ld_stage(St& S, int e,
                                         const __half* __restrict__ pt,
                                         const float* __restrict__ emb,
                                         const short* e_meta, const short* e_node,
                                         int j0, int r2) {
  const int meta = e_meta[e];
  const int dep = meta & 0x1FFF;
  const __half* hb = pt + (((size_t)dep) << 20) + (((size_t)j0) << 10) + r2;
  S.p0 = __half22float2(*(const __half2*)(hb));
  S.p1 = __half22float2(*(const __half2*)(hb + DD));
  S.p2 = __half22float2(*(const __half2*)(hb + 2 * DD));
  S.p3 = __half22float2(*(const __half2*)(hb + 3 * DD));
  if (meta & 0x8000) {
    const float2 xx = *(const float2*)(emb + (((size_t)e_node[e]) << 10) + r2);
    S.x0 = xx.x; S.x1 = xx.y;
  }
}

__device__ __forceinline__ float2 mul2s(float2 a, float s) {
  float2 r; r.x = a.x * s; r.y = a.y * s; return r;
}
__device__ __forceinline__ float2 max2(float2 a, float2 b) {
  float2 r; r.x = fmaxf(a.x, b.x); r.y = fmaxf(a.y, b.y); return r;
}

__device__ __forceinline__ void cmp_stage(const St& S, int e, float2& m0, float2& m1,
                                          float2& m2, float2& m3,
                                          float (*z_loc)[4], float (*s_part)[4],
                                          const short* e_child, const short* e_meta,
                                          const short* e_node, int tid) {
  const int meta = e_meta[e];
  const float4 u = relu4(*(const float4*)z_loc[e_child[e]]);  // 4 cols
  if (meta & (1 << 14)) {  // first child of node
    m0 = mul2s(S.p0, u.x); m1 = mul2s(S.p1, u.y);
    m2 = mul2s(S.p2, u.z); m3 = mul2s(S.p3, u.w);
  } else {
    m0 = max2(m0, mul2s(S.p0, u.x)); m1 = max2(m1, mul2s(S.p1, u.y));
    m2 = max2(m2, mul2s(S.p2, u.z)); m3 = max2(m3, mul2s(S.p3, u.w));
  }
  if (meta & 0x8000) {  // last child: finish node
    float4 acc;
    acc.x = fmaf(S.x1, m0.y, S.x0 * m0.x);
    acc.y = fmaf(S.x1, m1.y, S.x0 * m1.x);
    acc.z = fmaf(S.x1, m2.y, S.x0 * m2.x);
    acc.w = fmaf(S.x1, m3.y, S.x0 * m3.x);
    // 64-lane butterfly (fixed order -> deterministic)
#pragma unroll
    for (int off = 1; off < 64; off <<= 1) {
      acc.x += __shfl_xor(acc.x, off, 64);
      acc.y += __shfl_xor(acc.y, off, 64);
      acc.z += __shfl_xor(acc.z, off, 64);
      acc.w += __shfl_xor(acc.w, off, 64);
    }
    if ((tid & 63) == 0) *(float4*)s_part[tid >> 6] = acc;
    __syncthreads();
    if (tid < 4) {
      float s = 0.f;
#pragma unroll
      for (int k = 0; k < 8; ++k) s += s_part[k][tid];
      z_loc[e_node[e]][tid] = s;
    }
    __syncthreads();
  }
}

__global__ __launch_bounds__(NT, 1) void walk_kernel(
    const float* __restrict__ emb, const int* __restrict__ cidx,
    const int* __restrict__ cdep, const unsigned char* __restrict__ cmask,
    float* __restrict__ out, const __half* __restrict__ pt) {
  __shared__ float z_loc[NN][4];
  __shared__ short s_ci[NN][CC];
  __shared__ short s_cd[NN][CC];
  __shared__ short s_nc[NN];
  __shared__ int s_pfx[NN];
  __shared__ unsigned char s_reach[NN];
  __shared__ short s_e_child[NN * CC];  // child-stream (topo order)
  __shared__ short s_e_meta[NN * CC];   // dep | first<<14 | last<<15
  __shared__ short s_e_node[NN * CC];
  __shared__ int s_NE;
  __shared__ int s_flag;
  __shared__ float s_part[8][4];

  const int tid = threadIdx.x;
  const int j0 = blockIdx.x << 2;  // 4 exclusive columns per block
  const int r2 = tid << 1;         // 2 rows per thread

  // ---- Phase 1: schedule build (LDS only, identical in every block) ----
  if (tid == 0)
    s_flag = (cmask[1021] == 1 && cmask[1022] == 1 && cmask[1023] == 1);
  __syncthreads();
  const bool m_u8 = (s_flag != 0);
  const int* m32 = (const int*)cmask;
  if (tid < NN) {
    int nc = 0;
#pragma unroll
    for (int c = 0; c < CC; ++c) {
      bool mk = m_u8 ? (cmask[tid * CC + c] != 0) : (m32[tid * CC + c] != 0);
      if (mk) {
        s_ci[tid][nc] = (short)cidx[tid * CC + c];
        s_cd[tid][nc] = (short)cdep[tid * CC + c];
        ++nc;
      }
    }
    s_nc[tid] = (short)nc;
    s_reach[tid] = (tid == ROOT) ? 1 : 0;
  }
  __syncthreads();

  // Reachability fixpoint (root downward; <= depth passes)
  for (int it = 0; it < NN + 2; ++it) {
    if (tid == 0) s_flag = 0;
    __syncthreads();
    if (tid < NN && s_reach[tid] && s_nc[tid] > 0) {
      for (int c = 0; c < s_nc[tid]; ++c) {
        const int ch = s_ci[tid][c];
        if (!s_reach[ch]) { s_reach[ch] = 1; s_flag = 1; }
      }
    }
    __syncthreads();
    const int chg = s_flag;
    __syncthreads();
    if (!chg) break;
  }

  // Prefix-sum of per-node child counts (reachable internal only)
  const int wgt = (tid < NN && s_reach[tid] && s_nc[tid] > 0) ? (int)s_nc[tid] : 0;
  if (tid < NN) s_pfx[tid] = wgt;
  __syncthreads();
  for (int off = 1; off < NN; off <<= 1) {
    int v = 0;
    if (tid < NN && tid >= off) v = s_pfx[tid - off];
    __syncthreads();
    if (tid < NN) s_pfx[tid] += v;
    __syncthreads();
  }
  // Emit child-stream entries (ascending node index = topological order)
  if (tid < NN && wgt > 0) {
    const int st = s_pfx[tid] - wgt;
    for (int c = 0; c < wgt; ++c) {
      s_e_child[st + c] = s_ci[tid][c];
      int meta = (int)s_cd[tid][c];
      if (c == 0) meta |= 1 << 14;
      if (c == wgt - 1) meta |= 1 << 15;
      s_e_meta[st + c] = (short)meta;
      s_e_node[st + c] = (short)tid;
    }
  }
  if (tid == NN - 1) s_NE = s_pfx[NN - 1];

  // Init z_loc from embeddings (leaf z = x; internal overwritten in topo order)
  if (tid < NN) {
    const float4 e = *(const float4*)(emb + (((size_t)tid) << 10) + j0);
    *(float4*)z_loc[tid] = e;
  }
  __syncthreads();
  const int NE = s_NE;

  // ---- Phase 2: 4-deep pipelined serial walk (static stage names) ----
  St A, B, C, D;
  float2 m0, m1, m2, m3;
  if (NE > 0) ld_stage(A, 0, pt, emb, s_e_meta, s_e_node, j0, r2);
  if (NE > 1) ld_stage(B, 1, pt, emb, s_e_meta, s_e_node, j0, r2);
  if (NE > 2) ld_stage(C, 2, pt, emb, s_e_meta, s_e_node, j0, r2);
  int e = 0;
  while (e < NE) {
    if (e + 3 < NE) ld_stage(D, e + 3, pt, emb, s_e_meta, s_e_node, j0, r2);
    cmp_stage(A, e, m0, m1, m2, m3, z_loc, s_part, s_e_child, s_e_meta, s_e_node, tid);
    if (++e >= NE) break;
    if (e + 3 < NE) ld_stage(A, e + 3, pt, emb, s_e_meta, s_e_node, j0, r2);
    cmp_stage(B, e, m0, m1, m2, m3, z_loc, s_part, s_e_child, s_e_meta, s_e_node, tid);
    if (++e >= NE) break;
    if (e + 3 < NE) ld_stage(B, e + 3, pt, emb, s_e_meta, s_e_node, j0, r2);
    cmp_stage(C, e, m0, m1, m2, m3, z_loc, s_part, s_e_child, s_e_meta, s_e_node, tid);
    if (++e >= NE) break;
    if (e + 3 < NE) ld_stage(C, e + 3, pt, emb, s_e_meta, s_e_node, j0, r2);
    cmp_stage(D, e, m0, m1, m2, m3, z_loc, s_part, s_e_child, s_e_meta, s_e_node, tid);
    ++e;
  }

  // ---- Output: root z for this block's 4 columns ----
  if (tid < 4) out[j0 + tid] = z_loc[ROOT][tid];
}

extern "C" void kernel_launch(void* const* d_in, const int* in_sizes, int n_in,
                              void* d_out, int out_size, void* d_ws, size_t ws_size,
                              hipStream_t stream) {
  const float* emb = (const float*)d_in[0];
  const float* par = (const float*)d_in[1];
  const int* cidx = (const int*)d_in[2];
  const int* cdep = (const int*)d_in[3];
  const unsigned char* cmask = (const unsigned char*)d_in[4];
  float* out = (float*)d_out;

  // Pt destination: hipMalloc'd workspace if it fits (A/B vs static .bss),
  // else the static fallback. Deterministic across calls.
  __half* pt;
  if (ws_size >= PT_BYTES) {
    pt = (__half*)d_ws;
  } else {
    void* sym = nullptr;
    hipGetSymbolAddress(&sym, HIP_SYMBOL(g_Pth_fallback));
    pt = (__half*)sym;
  }

  hipLaunchKernelGGL(transpose_kernel, dim3(NP * 128), dim3(256), 0, stream,
                     par, pt);
  hipLaunchKernelGGL(walk_kernel, dim3(256), dim3(NT), 0, stream, emb, cidx,
                     cdep, cmask, out, (const __half*)pt);
}